// Round 5
// baseline (284.148 us; speedup 1.0000x reference)
//
#include <hip/hip_runtime.h>
#include <hip/hip_fp16.h>
#include <math.h>

// Strategy (R5): kernel is bound by HBM miss latency x limited concurrency
// (varying bytes/lines/instr count 1.5-3x left time pinned at ~52us).
// Fix: bin points into 8 row-strips and pin each strip to one XCD
// (blockIdx%8 -> XCD round-robin), so gathers hit the XCD-local L2
// (~200cy) instead of HBM (~900cy). Image pre-converted to fp16 (halves
// footprint; strip = 1.3MB << 4MB L2), convert pass row-swizzled to
// pre-warm the right XCD's L2. Taps: issue all 18 loads, then consume.

#define STRIP_SHIFT 8          // 2048 rows / 8 strips
#define MAIN_PAIR_STRIDE 1024  // pairs-per-bin covered per grid sweep

// ---------------- binning micro-kernels ----------------
__device__ __forceinline__ int point_bin(const float* points, int i) {
    int b = (int)points[(size_t)i * 5] >> STRIP_SHIFT;   // row coord = points[...,0]
    return b < 0 ? 0 : (b > 7 ? 7 : b);
}

__global__ void bin_init(int* cnt) {
    if (threadIdx.x < 8) cnt[threadIdx.x] = 0;
}

__global__ void bin_count(const float* __restrict__ points, int n, int* __restrict__ cnt) {
    const int i = blockIdx.x * 256 + (int)threadIdx.x;
    if (i < n) atomicAdd(&cnt[point_bin(points, i)], 1);
}

__global__ void bin_offsets(const int* __restrict__ cnt, int* __restrict__ off,
                            int* __restrict__ cur) {
    if (threadIdx.x == 0) {
        int s = 0;
        for (int k = 0; k < 8; ++k) { off[k] = s; s += cnt[k]; }
    }
    if (threadIdx.x < 8) cur[threadIdx.x] = 0;
}

__global__ void bin_scatter(const float* __restrict__ points, int n,
                            const int* __restrict__ off, int* __restrict__ cur,
                            int* __restrict__ perm) {
    const int i = blockIdx.x * 256 + (int)threadIdx.x;
    if (i < n) {
        const int b = point_bin(points, i);
        const int s = atomicAdd(&cur[b], 1);
        perm[off[b] + s] = i;
    }
}

// ---------------- fp16 convert, row-swizzled so strip k lands on XCD k ----------------
__global__ __launch_bounds__(256) void convert_img_f16(
    const float4* __restrict__ src, uint4* __restrict__ dst)
{
    // one block = one image row; block b -> row (b%8)*256 + b/8  (strip b%8)
    const int row = ((int)(blockIdx.x & 7) << 8) + (int)(blockIdx.x >> 3);
    const int t   = row * 256 + (int)threadIdx.x;        // 256 float4-pairs per row
    const float4 a = src[(size_t)t * 2];
    const float4 b = src[(size_t)t * 2 + 1];
    union { __half2 h[4]; uint4 u; } o;
    o.h[0] = __float22half2_rn(make_float2(a.x, a.y));
    o.h[1] = __float22half2_rn(make_float2(a.z, a.w));
    o.h[2] = __float22half2_rn(make_float2(b.x, b.y));
    o.h[3] = __float22half2_rn(make_float2(b.z, b.w));
    dst[t] = o.u;
}

// ---------------- main gather kernel ----------------
template<bool CLAMP>
__device__ __forceinline__ void tap_addr(float ci, float cj,
                                         float& di, float& dj, int& base)
{
    float fi = floorf(ci), fj = floorf(cj);
    if (CLAMP) {
        fi = fminf(fmaxf(fi, 0.f), 2046.f);
        fj = fminf(fmaxf(fj, 0.f), 2046.f);
    }
    di = ci - fi; dj = cj - fj;
    if (CLAMP) {
        di = fminf(fmaxf(di, 0.f), 1.f);
        dj = fminf(fmaxf(dj, 0.f), 1.f);
    }
    base = ((int)fi << 11) + (int)fj;
}

__device__ __forceinline__ float tap_eval(const uint2& q0, const uint2& q1,
                                          float di, float dj, int base)
{
    const int sh = (base & 1) << 4;
    const unsigned p0 = (unsigned)((((unsigned long long)q0.y << 32) | q0.x) >> sh);
    const unsigned p1 = (unsigned)((((unsigned long long)q1.y << 32) | q1.x) >> sh);
    const float2 f0 = __half22float2(*reinterpret_cast<const __half2*>(&p0));
    const float2 f1 = __half22float2(*reinterpret_cast<const __half2*>(&p1));
    const float top = fmaf(f0.y - f0.x, dj, f0.x);
    const float bot = fmaf(f1.y - f1.x, dj, f1.x);
    return fmaf(bot - top, di, top);
}

template<bool CLAMP>
__device__ __forceinline__ void accumulate16(
    const __half* __restrict__ img, int lane, int half,
    float A00, float A01, float A10, float A11, float px, float py,
    float& sum_in, float& sq_in, float& sum_out, float& sq_out)
{
    // interior: 8 of 16 8x8 tiles (4x4 tile grid); tap 8 = ring sample
    const int r8 = lane >> 3;
    const int c8 = lane & 7;
    const float sy0 = fmaf((float)r8, 0.0625f, 0.03125f) - 1.0f;
    const float sx0 = fmaf((float)c8, 0.0625f, 0.03125f) - 1.0f;
    const float ci0 = fmaf(A00, sy0, fmaf(A01, sx0, px));
    const float cj0 = fmaf(A10, sy0, fmaf(A11, sx0, py));
    const float A00h = A00 * 0.5f, A01h = A01 * 0.5f;
    const float A10h = A10 * 0.5f, A11h = A11 * 0.5f;

    float di[9], dj[9];
    int   base[9];
    uint2 qa[9], qb[9];

    // ---- phase A: addresses + issue all loads ----
    #pragma unroll
    for (int t = 0; t < 8; ++t) {
        const int tile = half * 8 + t;
        const float ftr = (float)(tile >> 2);
        const float ftc = (float)(tile & 3);
        const float ci = fmaf(A00h, ftr, fmaf(A01h, ftc, ci0));
        const float cj = fmaf(A10h, ftr, fmaf(A11h, ftc, cj0));
        tap_addr<CLAMP>(ci, cj, di[t], dj[t], base[t]);
        const int even = base[t] & ~1;
        __builtin_memcpy(&qa[t], img + even, 8);
        __builtin_memcpy(&qb[t], img + even + 2048, 8);
    }
    {   // ring tap
        const int n = half * 62 + lane;
        int row = 0, col = 0;
        if (n < 32)      { row = 0;                   col = n; }
        else if (n < 92) { row = 1 + ((n - 32) >> 1); col = (n & 1) * 31; }
        else             { row = 31;                  col = n - 92; }
        const float sy = (fmaf((float)row, 0.0625f, 0.03125f) - 1.0f) * 1.0625f;
        const float sx = (fmaf((float)col, 0.0625f, 0.03125f) - 1.0f) * 1.0625f;
        float ci = fmaf(A00, sy, fmaf(A01, sx, px));
        float cj = fmaf(A10, sy, fmaf(A11, sx, py));
        if (lane >= 62) { ci = px; cj = py; }   // in-range dummy
        tap_addr<CLAMP>(ci, cj, di[8], dj[8], base[8]);
        const int even = base[8] & ~1;
        __builtin_memcpy(&qa[8], img + even, 8);
        __builtin_memcpy(&qb[8], img + even + 2048, 8);
    }

    // ---- phase B: consume ----
    float s0 = 0.f, q0 = 0.f, s1 = 0.f, q1 = 0.f;
    #pragma unroll
    for (int t = 0; t < 8; ++t) {
        const float v = tap_eval(qa[t], qb[t], di[t], dj[t], base[t]);
        if (t & 1) { s1 += v; q1 = fmaf(v, v, q1); }
        else       { s0 += v; q0 = fmaf(v, v, q0); }
    }
    sum_in = s0 + s1;
    sq_in  = q0 + q1;

    const float vr = tap_eval(qa[8], qb[8], di[8], dj[8], base[8]);
    sum_out = (lane < 62) ? vr : 0.f;
    sq_out  = (lane < 62) ? vr * vr : 0.f;
}

__global__ __launch_bounds__(256) void contrast_kernel_f16_binned(
    const float* __restrict__ points,   // (S*P, 5)
    const float* __restrict__ mask,     // (S*P)
    const __half* __restrict__ img,     // (2048, 2048) fp16 in d_ws
    const int* __restrict__ perm,       // binned point indices
    const int* __restrict__ cnt,        // per-bin counts
    const int* __restrict__ off,        // per-bin offsets
    float* __restrict__ out)            // (S*P)
{
    __shared__ float partial[4][4];

    const int wib   = (int)(threadIdx.x >> 6);   // 0..3
    const int lane  = (int)(threadIdx.x & 63u);
    const int local = wib >> 1;                  // which of the 2 points
    const int half  = wib & 1;                   // which half of the work
    const int bin   = (int)(blockIdx.x & 7);     // strip / XCD
    const int c     = cnt[bin];
    const int o     = off[bin];

    for (int j = (int)(blockIdx.x >> 3); 2 * j < c; j += MAIN_PAIR_STRIDE) {
        const int  k     = 2 * j + local;
        const bool valid = k < c;
        const int  pid   = perm[o + (valid ? k : 0)];

        const float* pt = points + (size_t)pid * 5;
        const float px = pt[0];
        const float py = pt[1];
        const float a  = pt[2];
        const float b  = pt[3];
        const float th = pt[4];

        float sn, cs;
        sincosf(th, &sn, &cs);
        const float A00 = a * cs, A01 = -b * sn;   // i (row)
        const float A10 = a * sn, A11 =  b * cs;   // j (col)

        const float Ri = (fabsf(A00) + fabsf(A01)) * 1.04f;
        const float Rj = (fabsf(A10) + fabsf(A11)) * 1.04f;
        const bool interior = (px >= Ri + 0.5f) && (px <= 2046.0f - Ri) &&
                              (py >= Rj + 0.5f) && (py <= 2046.0f - Rj);

        float sum_in, sq_in, sum_out, sq_out;
        if (interior) {
            accumulate16<false>(img, lane, half, A00, A01, A10, A11, px, py,
                                sum_in, sq_in, sum_out, sq_out);
        } else {
            accumulate16<true>(img, lane, half, A00, A01, A10, A11, px, py,
                               sum_in, sq_in, sum_out, sq_out);
        }

        #pragma unroll
        for (int sft = 32; sft > 0; sft >>= 1) {
            sum_in  += __shfl_xor(sum_in,  sft);
            sq_in   += __shfl_xor(sq_in,   sft);
            sum_out += __shfl_xor(sum_out, sft);
            sq_out  += __shfl_xor(sq_out,  sft);
        }

        if (lane == 0) {
            partial[wib][0] = sum_in;
            partial[wib][1] = sq_in;
            partial[wib][2] = sum_out;
            partial[wib][3] = sq_out;
        }
        __syncthreads();

        if (valid && half == 0 && lane == 0) {
            const float S_in  = partial[wib][0] + partial[wib + 1][0];
            const float Q_in  = partial[wib][1] + partial[wib + 1][1];
            const float S_out = partial[wib][2] + partial[wib + 1][2];
            const float Q_out = partial[wib][3] + partial[wib + 1][3];
            const float ni = 1024.f, no = 124.f;
            const float m_in  = S_in  / ni;
            const float m_out = S_out / no;
            const float v_in  = (Q_in  - ni * m_in  * m_in ) / (ni - 1.f);
            const float v_out = (Q_out - no * m_out * m_out) / (no - 1.f);
            const float contrast = (m_in - m_out) / sqrtf(v_in + v_out + 1e-8f);
            out[pid] = contrast * mask[pid];
        }
        __syncthreads();   // protect partial[] reuse in next iteration
    }
}

// ---------------- fp32 fast path (R3) — fallback if ws too small ----------------
__global__ __launch_bounds__(256) void contrast_kernel_fast(
    const float* __restrict__ points, const float* __restrict__ mask,
    const float* __restrict__ img, float* __restrict__ out, int n_points)
{
    constexpr int W = 2048;
    constexpr float fImax = 2046.f, fJmax = 2046.f;
    __shared__ float partial[4][4];
    const int wib  = (int)(threadIdx.x >> 6);
    const int lane = (int)(threadIdx.x & 63u);
    const int pid  = blockIdx.x * 2 + (wib >> 1);
    const int half = wib & 1;
    if (pid >= n_points) return;
    const float* pt = points + (size_t)pid * 5;
    const float px = pt[0], py = pt[1], a = pt[2], b = pt[3], th = pt[4];
    float sn, cs; sincosf(th, &sn, &cs);
    const float A00 = a * cs, A01 = -b * sn, A10 = a * sn, A11 = b * cs;
    const int r8 = lane >> 3, c8 = lane & 7;
    const float sy0 = fmaf((float)r8, 0.0625f, 0.03125f) - 1.0f;
    const float sx0 = fmaf((float)c8, 0.0625f, 0.03125f) - 1.0f;
    const float ci0 = fmaf(A00, sy0, fmaf(A01, sx0, px));
    const float cj0 = fmaf(A10, sy0, fmaf(A11, sx0, py));
    const float A00h = A00 * 0.5f, A01h = A01 * 0.5f;
    const float A10h = A10 * 0.5f, A11h = A11 * 0.5f;
    float s0 = 0.f, q0 = 0.f, s1 = 0.f, q1 = 0.f;
    #pragma unroll
    for (int t = 0; t < 8; ++t) {
        const int tile = half * 8 + t;
        const float ftr = (float)(tile >> 2), ftc = (float)(tile & 3);
        const float ci = fmaf(A00h, ftr, fmaf(A01h, ftc, ci0));
        const float cj = fmaf(A10h, ftr, fmaf(A11h, ftc, cj0));
        const float fi = fminf(fmaxf(floorf(ci), 0.f), fImax);
        const float fj = fminf(fmaxf(floorf(cj), 0.f), fJmax);
        const float di = fminf(fmaxf(ci - fi, 0.f), 1.f);
        const float dj = fminf(fmaxf(cj - fj, 0.f), 1.f);
        const float* p0 = img + (((int)fi << 11) + (int)fj);
        float2 r0, r1;
        __builtin_memcpy(&r0, p0, sizeof(float2));
        __builtin_memcpy(&r1, p0 + W, sizeof(float2));
        const float top = fmaf(r0.y - r0.x, dj, r0.x);
        const float bot = fmaf(r1.y - r1.x, dj, r1.x);
        const float v = fmaf(bot - top, di, top);
        if (t & 1) { s1 += v; q1 = fmaf(v, v, q1); }
        else       { s0 += v; q0 = fmaf(v, v, q0); }
    }
    float sum_in = s0 + s1, sq_in = q0 + q1;
    float sum_out = 0.f, sq_out = 0.f;
    const int n = half * 62 + lane;
    if (lane < 62) {
        int row, col;
        if (n < 32)      { row = 0;                   col = n; }
        else if (n < 92) { row = 1 + ((n - 32) >> 1); col = (n & 1) * 31; }
        else             { row = 31;                  col = n - 92; }
        const float sy = (fmaf((float)row, 0.0625f, 0.03125f) - 1.0f) * 1.0625f;
        const float sx = (fmaf((float)col, 0.0625f, 0.03125f) - 1.0f) * 1.0625f;
        const float ci = fmaf(A00, sy, fmaf(A01, sx, px));
        const float cj = fmaf(A10, sy, fmaf(A11, sx, py));
        const float fi = fminf(fmaxf(floorf(ci), 0.f), fImax);
        const float fj = fminf(fmaxf(floorf(cj), 0.f), fJmax);
        const float di = fminf(fmaxf(ci - fi, 0.f), 1.f);
        const float dj = fminf(fmaxf(cj - fj, 0.f), 1.f);
        const float* p0 = img + (((int)fi << 11) + (int)fj);
        float2 r0, r1;
        __builtin_memcpy(&r0, p0, sizeof(float2));
        __builtin_memcpy(&r1, p0 + W, sizeof(float2));
        const float top = fmaf(r0.y - r0.x, dj, r0.x);
        const float bot = fmaf(r1.y - r1.x, dj, r1.x);
        const float v = fmaf(bot - top, di, top);
        sum_out = v; sq_out = v * v;
    }
    #pragma unroll
    for (int sft = 32; sft > 0; sft >>= 1) {
        sum_in  += __shfl_xor(sum_in,  sft);
        sq_in   += __shfl_xor(sq_in,   sft);
        sum_out += __shfl_xor(sum_out, sft);
        sq_out  += __shfl_xor(sq_out,  sft);
    }
    if (lane == 0) {
        partial[wib][0] = sum_in; partial[wib][1] = sq_in;
        partial[wib][2] = sum_out; partial[wib][3] = sq_out;
    }
    __syncthreads();
    if (lane == 0 && half == 0) {
        const float S_in = partial[wib][0] + partial[wib + 1][0];
        const float Q_in = partial[wib][1] + partial[wib + 1][1];
        const float S_out = partial[wib][2] + partial[wib + 1][2];
        const float Q_out = partial[wib][3] + partial[wib + 1][3];
        const float ni = 1024.f, no = 124.f;
        const float m_in = S_in / ni, m_out = S_out / no;
        const float v_in  = (Q_in  - ni * m_in  * m_in ) / (ni - 1.f);
        const float v_out = (Q_out - no * m_out * m_out) / (no - 1.f);
        const float contrast = (m_in - m_out) / sqrtf(v_in + v_out + 1e-8f);
        out[pid] = contrast * mask[pid];
    }
}

// ---------------- generic fallback ----------------
__global__ __launch_bounds__(256) void contrast_kernel_generic(
    const float* __restrict__ points, const float* __restrict__ mask,
    const float* __restrict__ img, const float* __restrict__ st_in,
    const float* __restrict__ st_out, float* __restrict__ out,
    int n_points, int n_in, int n_out, int Himg, int Wimg)
{
    const int wave = (int)((blockIdx.x * (unsigned)blockDim.x + threadIdx.x) >> 6);
    const int lane = (int)(threadIdx.x & 63u);
    if (wave >= n_points) return;
    const float* pt = points + (size_t)wave * 5;
    const float px = pt[0], py = pt[1], a = pt[2], b = pt[3], th = pt[4];
    float sn, cs; sincosf(th, &sn, &cs);
    const float A00 = a * cs, A01 = -b * sn, A10 = a * sn, A11 = b * cs;
    const float fImax = (float)(Himg - 2), fJmax = (float)(Wimg - 2);
    float sum_in = 0.f, sq_in = 0.f;
    for (int base = 0; base < n_in; base += 64) {
        const int n = base + lane;
        if (n < n_in) {
            const float sy = st_in[n * 3 + 0], sx = st_in[n * 3 + 1];
            const float ci = fmaf(A00, sy, fmaf(A01, sx, px));
            const float cj = fmaf(A10, sy, fmaf(A11, sx, py));
            const float fi = fminf(fmaxf(floorf(ci), 0.f), fImax);
            const float fj = fminf(fmaxf(floorf(cj), 0.f), fJmax);
            const float di = fminf(fmaxf(ci - fi, 0.f), 1.f);
            const float dj = fminf(fmaxf(cj - fj, 0.f), 1.f);
            const float* p0 = img + ((int)fi * Wimg + (int)fj);
            const float v00 = p0[0], v01 = p0[1], v10 = p0[Wimg], v11 = p0[Wimg + 1];
            const float top = fmaf(v01 - v00, dj, v00);
            const float bot = fmaf(v11 - v10, dj, v10);
            const float v = fmaf(bot - top, di, top);
            sum_in += v; sq_in = fmaf(v, v, sq_in);
        }
    }
    float sum_out = 0.f, sq_out = 0.f;
    for (int base = 0; base < n_out; base += 64) {
        const int n = base + lane;
        if (n < n_out) {
            const float sy = st_out[n * 3 + 0], sx = st_out[n * 3 + 1];
            const float ci = fmaf(A00, sy, fmaf(A01, sx, px));
            const float cj = fmaf(A10, sy, fmaf(A11, sx, py));
            const float fi = fminf(fmaxf(floorf(ci), 0.f), fImax);
            const float fj = fminf(fmaxf(floorf(cj), 0.f), fJmax);
            const float di = fminf(fmaxf(ci - fi, 0.f), 1.f);
            const float dj = fminf(fmaxf(cj - fj, 0.f), 1.f);
            const float* p0 = img + ((int)fi * Wimg + (int)fj);
            const float v00 = p0[0], v01 = p0[1], v10 = p0[Wimg], v11 = p0[Wimg + 1];
            const float top = fmaf(v01 - v00, dj, v00);
            const float bot = fmaf(v11 - v10, dj, v10);
            const float v = fmaf(bot - top, di, top);
            sum_out += v; sq_out = fmaf(v, v, sq_out);
        }
    }
    #pragma unroll
    for (int sft = 32; sft > 0; sft >>= 1) {
        sum_in += __shfl_xor(sum_in, sft);  sq_in += __shfl_xor(sq_in, sft);
        sum_out += __shfl_xor(sum_out, sft); sq_out += __shfl_xor(sq_out, sft);
    }
    if (lane == 0) {
        const float ni = (float)n_in, no = (float)n_out;
        const float m_in = sum_in / ni, m_out = sum_out / no;
        const float v_in = (sq_in - ni * m_in * m_in) / (ni - 1.f);
        const float v_out = (sq_out - no * m_out * m_out) / (no - 1.f);
        const float contrast = (m_in - m_out) / sqrtf(v_in + v_out + 1e-8f);
        out[wave] = contrast * mask[wave];
    }
}

extern "C" void kernel_launch(void* const* d_in, const int* in_sizes, int n_in_bufs,
                              void* d_out, int out_size, void* d_ws, size_t ws_size,
                              hipStream_t stream) {
    (void)n_in_bufs; (void)out_size;
    const float* points = (const float*)d_in[0];
    const float* mask   = (const float*)d_in[1];
    const float* img    = (const float*)d_in[2];
    const float* st_in  = (const float*)d_in[3];
    const float* st_out = (const float*)d_in[4];
    float* out = (float*)d_out;

    const int n_points = in_sizes[0] / 5;
    const int n_in     = in_sizes[3] / 3;
    const int n_out    = in_sizes[4] / 3;
    const int hw       = in_sizes[2];

    const bool canonical = (n_in == 1024 && n_out == 124 && hw == 2048 * 2048);

    // ws layout: [fp16 image | cnt[8] | off[8] | cur[8] | perm[n_points]]
    const size_t img_bytes = (size_t)hw * sizeof(__half);
    const size_t meta_off  = (img_bytes + 255) & ~(size_t)255;
    const size_t need      = meta_off + (size_t)(24 + n_points) * 4 + 64;

    if (canonical && ws_size >= need && n_points > 0) {
        __half* img16 = (__half*)d_ws;
        int* meta = (int*)((char*)d_ws + meta_off);
        int* cnt  = meta;
        int* off  = meta + 8;
        int* cur  = meta + 16;
        int* perm = meta + 24;

        const int nb = (n_points + 255) / 256;
        bin_init   <<<1,  64, 0, stream>>>(cnt);
        bin_count  <<<nb, 256, 0, stream>>>(points, n_points, cnt);
        bin_offsets<<<1,  64, 0, stream>>>(cnt, off, cur);
        bin_scatter<<<nb, 256, 0, stream>>>(points, n_points, off, cur, perm);
        convert_img_f16<<<2048, 256, 0, stream>>>((const float4*)img, (uint4*)img16);
        contrast_kernel_f16_binned<<<8 * MAIN_PAIR_STRIDE, 256, 0, stream>>>(
            points, mask, img16, perm, cnt, off, out);
    } else if (canonical) {
        const int blocks = (n_points + 1) / 2;
        contrast_kernel_fast<<<blocks, 256, 0, stream>>>(points, mask, img, out, n_points);
    } else {
        int Wimg = 1;
        while ((long long)Wimg * Wimg < (long long)hw) Wimg <<= 1;
        const int Himg = hw / Wimg;
        const int blocks = (n_points + 3) / 4;
        contrast_kernel_generic<<<blocks, 256, 0, stream>>>(points, mask, img, st_in, st_out,
                                                            out, n_points, n_in, n_out, Himg, Wimg);
    }
}

// Round 6
// 135.347 us; speedup vs baseline: 2.0994x; 2.0994x over previous
//
#include <hip/hip_runtime.h>
#include <hip/hip_fp16.h>
#include <math.h>

// R6: identical gather strategy to R5 (8 row-strip bins pinned to XCDs via
// blockIdx%8, fp16 image in ws), but binning rebuilt with LDS histograms:
// 512 global atomics total instead of 32768 (R5's bin_count/bin_scatter were
// 90us each from 8-address atomic serialization).

#define STRIP_SHIFT 8          // 2048 rows / 8 strips
#define MAIN_PAIR_STRIDE 1024  // pairs-per-bin covered per grid sweep

__device__ __forceinline__ int point_bin_row(float row) {
    int b = (int)row >> STRIP_SHIFT;
    return b < 0 ? 0 : (b > 7 ? 7 : b);
}

// ---------------- binning: LDS-histogram version ----------------
__global__ void bin_init(int* meta) {            // cnt[8] | cur[8]
    if (threadIdx.x < 16) meta[threadIdx.x] = 0;
}

__global__ __launch_bounds__(256) void bin_count_lds(
    const float* __restrict__ points, int n, int* __restrict__ cnt)
{
    __shared__ int hist[8];
    if (threadIdx.x < 8) hist[threadIdx.x] = 0;
    __syncthreads();
    const int i = blockIdx.x * 256 + (int)threadIdx.x;
    if (i < n) atomicAdd(&hist[point_bin_row(points[(size_t)i * 5])], 1);
    __syncthreads();
    if (threadIdx.x < 8 && hist[threadIdx.x] > 0)
        atomicAdd(&cnt[threadIdx.x], hist[threadIdx.x]);
}

__global__ void bin_offsets(const int* __restrict__ cnt, int* __restrict__ off) {
    if (threadIdx.x == 0) {
        int s = 0;
        for (int k = 0; k < 8; ++k) { off[k] = s; s += cnt[k]; }
    }
}

__global__ __launch_bounds__(256) void bin_scatter_lds(
    const float* __restrict__ points, int n,
    const int* __restrict__ off, int* __restrict__ cur,
    int* __restrict__ perm)
{
    __shared__ int hist[8];
    __shared__ int base[8];
    if (threadIdx.x < 8) hist[threadIdx.x] = 0;
    __syncthreads();
    const int i = blockIdx.x * 256 + (int)threadIdx.x;
    int b = 0, rank = 0;
    if (i < n) {
        b = point_bin_row(points[(size_t)i * 5]);
        rank = atomicAdd(&hist[b], 1);           // rank within block within bin
    }
    __syncthreads();
    if (threadIdx.x < 8) {
        base[threadIdx.x] = (hist[threadIdx.x] > 0)
            ? atomicAdd(&cur[threadIdx.x], hist[threadIdx.x]) : 0;
    }
    __syncthreads();
    if (i < n) perm[off[b] + base[b] + rank] = i;
}

// ---------------- fp16 convert, row-swizzled so strip k lands on XCD k ----------------
__global__ __launch_bounds__(256) void convert_img_f16(
    const float4* __restrict__ src, uint4* __restrict__ dst)
{
    // one block = one image row; block b -> row (b%8)*256 + b/8 (strip b%8)
    const int row = ((int)(blockIdx.x & 7) << 8) + (int)(blockIdx.x >> 3);
    const int t   = row * 256 + (int)threadIdx.x;
    const float4 a = src[(size_t)t * 2];
    const float4 b = src[(size_t)t * 2 + 1];
    union { __half2 h[4]; uint4 u; } o;
    o.h[0] = __float22half2_rn(make_float2(a.x, a.y));
    o.h[1] = __float22half2_rn(make_float2(a.z, a.w));
    o.h[2] = __float22half2_rn(make_float2(b.x, b.y));
    o.h[3] = __float22half2_rn(make_float2(b.z, b.w));
    dst[t] = o.u;
}

// ---------------- main gather kernel (unchanged from R5) ----------------
template<bool CLAMP>
__device__ __forceinline__ void tap_addr(float ci, float cj,
                                         float& di, float& dj, int& base)
{
    float fi = floorf(ci), fj = floorf(cj);
    if (CLAMP) {
        fi = fminf(fmaxf(fi, 0.f), 2046.f);
        fj = fminf(fmaxf(fj, 0.f), 2046.f);
    }
    di = ci - fi; dj = cj - fj;
    if (CLAMP) {
        di = fminf(fmaxf(di, 0.f), 1.f);
        dj = fminf(fmaxf(dj, 0.f), 1.f);
    }
    base = ((int)fi << 11) + (int)fj;
}

__device__ __forceinline__ float tap_eval(const uint2& q0, const uint2& q1,
                                          float di, float dj, int base)
{
    const int sh = (base & 1) << 4;
    const unsigned p0 = (unsigned)((((unsigned long long)q0.y << 32) | q0.x) >> sh);
    const unsigned p1 = (unsigned)((((unsigned long long)q1.y << 32) | q1.x) >> sh);
    const float2 f0 = __half22float2(*reinterpret_cast<const __half2*>(&p0));
    const float2 f1 = __half22float2(*reinterpret_cast<const __half2*>(&p1));
    const float top = fmaf(f0.y - f0.x, dj, f0.x);
    const float bot = fmaf(f1.y - f1.x, dj, f1.x);
    return fmaf(bot - top, di, top);
}

template<bool CLAMP>
__device__ __forceinline__ void accumulate16(
    const __half* __restrict__ img, int lane, int half,
    float A00, float A01, float A10, float A11, float px, float py,
    float& sum_in, float& sq_in, float& sum_out, float& sq_out)
{
    const int r8 = lane >> 3;
    const int c8 = lane & 7;
    const float sy0 = fmaf((float)r8, 0.0625f, 0.03125f) - 1.0f;
    const float sx0 = fmaf((float)c8, 0.0625f, 0.03125f) - 1.0f;
    const float ci0 = fmaf(A00, sy0, fmaf(A01, sx0, px));
    const float cj0 = fmaf(A10, sy0, fmaf(A11, sx0, py));
    const float A00h = A00 * 0.5f, A01h = A01 * 0.5f;
    const float A10h = A10 * 0.5f, A11h = A11 * 0.5f;

    float di[9], dj[9];
    int   base[9];
    uint2 qa[9], qb[9];

    #pragma unroll
    for (int t = 0; t < 8; ++t) {
        const int tile = half * 8 + t;
        const float ftr = (float)(tile >> 2);
        const float ftc = (float)(tile & 3);
        const float ci = fmaf(A00h, ftr, fmaf(A01h, ftc, ci0));
        const float cj = fmaf(A10h, ftr, fmaf(A11h, ftc, cj0));
        tap_addr<CLAMP>(ci, cj, di[t], dj[t], base[t]);
        const int even = base[t] & ~1;
        __builtin_memcpy(&qa[t], img + even, 8);
        __builtin_memcpy(&qb[t], img + even + 2048, 8);
    }
    {
        const int n = half * 62 + lane;
        int row = 0, col = 0;
        if (n < 32)      { row = 0;                   col = n; }
        else if (n < 92) { row = 1 + ((n - 32) >> 1); col = (n & 1) * 31; }
        else             { row = 31;                  col = n - 92; }
        const float sy = (fmaf((float)row, 0.0625f, 0.03125f) - 1.0f) * 1.0625f;
        const float sx = (fmaf((float)col, 0.0625f, 0.03125f) - 1.0f) * 1.0625f;
        float ci = fmaf(A00, sy, fmaf(A01, sx, px));
        float cj = fmaf(A10, sy, fmaf(A11, sx, py));
        if (lane >= 62) { ci = px; cj = py; }
        tap_addr<CLAMP>(ci, cj, di[8], dj[8], base[8]);
        const int even = base[8] & ~1;
        __builtin_memcpy(&qa[8], img + even, 8);
        __builtin_memcpy(&qb[8], img + even + 2048, 8);
    }

    float s0 = 0.f, q0 = 0.f, s1 = 0.f, q1 = 0.f;
    #pragma unroll
    for (int t = 0; t < 8; ++t) {
        const float v = tap_eval(qa[t], qb[t], di[t], dj[t], base[t]);
        if (t & 1) { s1 += v; q1 = fmaf(v, v, q1); }
        else       { s0 += v; q0 = fmaf(v, v, q0); }
    }
    sum_in = s0 + s1;
    sq_in  = q0 + q1;

    const float vr = tap_eval(qa[8], qb[8], di[8], dj[8], base[8]);
    sum_out = (lane < 62) ? vr : 0.f;
    sq_out  = (lane < 62) ? vr * vr : 0.f;
}

__global__ __launch_bounds__(256) void contrast_kernel_f16_binned(
    const float* __restrict__ points,
    const float* __restrict__ mask,
    const __half* __restrict__ img,
    const int* __restrict__ perm,
    const int* __restrict__ cnt,
    const int* __restrict__ off,
    float* __restrict__ out)
{
    __shared__ float partial[4][4];

    const int wib   = (int)(threadIdx.x >> 6);
    const int lane  = (int)(threadIdx.x & 63u);
    const int local = wib >> 1;
    const int half  = wib & 1;
    const int bin   = (int)(blockIdx.x & 7);
    const int c     = cnt[bin];
    const int o     = off[bin];

    for (int j = (int)(blockIdx.x >> 3); 2 * j < c; j += MAIN_PAIR_STRIDE) {
        const int  k     = 2 * j + local;
        const bool valid = k < c;
        const int  pid   = perm[o + (valid ? k : 0)];

        const float* pt = points + (size_t)pid * 5;
        const float px = pt[0];
        const float py = pt[1];
        const float a  = pt[2];
        const float b  = pt[3];
        const float th = pt[4];

        float sn, cs;
        sincosf(th, &sn, &cs);
        const float A00 = a * cs, A01 = -b * sn;
        const float A10 = a * sn, A11 =  b * cs;

        const float Ri = (fabsf(A00) + fabsf(A01)) * 1.04f;
        const float Rj = (fabsf(A10) + fabsf(A11)) * 1.04f;
        const bool interior = (px >= Ri + 0.5f) && (px <= 2046.0f - Ri) &&
                              (py >= Rj + 0.5f) && (py <= 2046.0f - Rj);

        float sum_in, sq_in, sum_out, sq_out;
        if (interior) {
            accumulate16<false>(img, lane, half, A00, A01, A10, A11, px, py,
                                sum_in, sq_in, sum_out, sq_out);
        } else {
            accumulate16<true>(img, lane, half, A00, A01, A10, A11, px, py,
                               sum_in, sq_in, sum_out, sq_out);
        }

        #pragma unroll
        for (int sft = 32; sft > 0; sft >>= 1) {
            sum_in  += __shfl_xor(sum_in,  sft);
            sq_in   += __shfl_xor(sq_in,   sft);
            sum_out += __shfl_xor(sum_out, sft);
            sq_out  += __shfl_xor(sq_out,  sft);
        }

        if (lane == 0) {
            partial[wib][0] = sum_in;
            partial[wib][1] = sq_in;
            partial[wib][2] = sum_out;
            partial[wib][3] = sq_out;
        }
        __syncthreads();

        if (valid && half == 0 && lane == 0) {
            const float S_in  = partial[wib][0] + partial[wib + 1][0];
            const float Q_in  = partial[wib][1] + partial[wib + 1][1];
            const float S_out = partial[wib][2] + partial[wib + 1][2];
            const float Q_out = partial[wib][3] + partial[wib + 1][3];
            const float ni = 1024.f, no = 124.f;
            const float m_in  = S_in  / ni;
            const float m_out = S_out / no;
            const float v_in  = (Q_in  - ni * m_in  * m_in ) / (ni - 1.f);
            const float v_out = (Q_out - no * m_out * m_out) / (no - 1.f);
            const float contrast = (m_in - m_out) / sqrtf(v_in + v_out + 1e-8f);
            out[pid] = contrast * mask[pid];
        }
        __syncthreads();
    }
}

// ---------------- fp32 fast path fallback ----------------
__global__ __launch_bounds__(256) void contrast_kernel_fast(
    const float* __restrict__ points, const float* __restrict__ mask,
    const float* __restrict__ img, float* __restrict__ out, int n_points)
{
    constexpr int W = 2048;
    constexpr float fImax = 2046.f, fJmax = 2046.f;
    __shared__ float partial[4][4];
    const int wib  = (int)(threadIdx.x >> 6);
    const int lane = (int)(threadIdx.x & 63u);
    const int pid  = blockIdx.x * 2 + (wib >> 1);
    const int half = wib & 1;
    if (pid >= n_points) return;
    const float* pt = points + (size_t)pid * 5;
    const float px = pt[0], py = pt[1], a = pt[2], b = pt[3], th = pt[4];
    float sn, cs; sincosf(th, &sn, &cs);
    const float A00 = a * cs, A01 = -b * sn, A10 = a * sn, A11 = b * cs;
    const int r8 = lane >> 3, c8 = lane & 7;
    const float sy0 = fmaf((float)r8, 0.0625f, 0.03125f) - 1.0f;
    const float sx0 = fmaf((float)c8, 0.0625f, 0.03125f) - 1.0f;
    const float ci0 = fmaf(A00, sy0, fmaf(A01, sx0, px));
    const float cj0 = fmaf(A10, sy0, fmaf(A11, sx0, py));
    const float A00h = A00 * 0.5f, A01h = A01 * 0.5f;
    const float A10h = A10 * 0.5f, A11h = A11 * 0.5f;
    float s0 = 0.f, q0 = 0.f, s1 = 0.f, q1 = 0.f;
    #pragma unroll
    for (int t = 0; t < 8; ++t) {
        const int tile = half * 8 + t;
        const float ftr = (float)(tile >> 2), ftc = (float)(tile & 3);
        const float ci = fmaf(A00h, ftr, fmaf(A01h, ftc, ci0));
        const float cj = fmaf(A10h, ftr, fmaf(A11h, ftc, cj0));
        const float fi = fminf(fmaxf(floorf(ci), 0.f), fImax);
        const float fj = fminf(fmaxf(floorf(cj), 0.f), fJmax);
        const float di = fminf(fmaxf(ci - fi, 0.f), 1.f);
        const float dj = fminf(fmaxf(cj - fj, 0.f), 1.f);
        const float* p0 = img + (((int)fi << 11) + (int)fj);
        float2 r0, r1;
        __builtin_memcpy(&r0, p0, sizeof(float2));
        __builtin_memcpy(&r1, p0 + W, sizeof(float2));
        const float top = fmaf(r0.y - r0.x, dj, r0.x);
        const float bot = fmaf(r1.y - r1.x, dj, r1.x);
        const float v = fmaf(bot - top, di, top);
        if (t & 1) { s1 += v; q1 = fmaf(v, v, q1); }
        else       { s0 += v; q0 = fmaf(v, v, q0); }
    }
    float sum_in = s0 + s1, sq_in = q0 + q1;
    float sum_out = 0.f, sq_out = 0.f;
    const int n = half * 62 + lane;
    if (lane < 62) {
        int row, col;
        if (n < 32)      { row = 0;                   col = n; }
        else if (n < 92) { row = 1 + ((n - 32) >> 1); col = (n & 1) * 31; }
        else             { row = 31;                  col = n - 92; }
        const float sy = (fmaf((float)row, 0.0625f, 0.03125f) - 1.0f) * 1.0625f;
        const float sx = (fmaf((float)col, 0.0625f, 0.03125f) - 1.0f) * 1.0625f;
        const float ci = fmaf(A00, sy, fmaf(A01, sx, px));
        const float cj = fmaf(A10, sy, fmaf(A11, sx, py));
        const float fi = fminf(fmaxf(floorf(ci), 0.f), fImax);
        const float fj = fminf(fmaxf(floorf(cj), 0.f), fJmax);
        const float di = fminf(fmaxf(ci - fi, 0.f), 1.f);
        const float dj = fminf(fmaxf(cj - fj, 0.f), 1.f);
        const float* p0 = img + (((int)fi << 11) + (int)fj);
        float2 r0, r1;
        __builtin_memcpy(&r0, p0, sizeof(float2));
        __builtin_memcpy(&r1, p0 + W, sizeof(float2));
        const float top = fmaf(r0.y - r0.x, dj, r0.x);
        const float bot = fmaf(r1.y - r1.x, dj, r1.x);
        const float v = fmaf(bot - top, di, top);
        sum_out = v; sq_out = v * v;
    }
    #pragma unroll
    for (int sft = 32; sft > 0; sft >>= 1) {
        sum_in  += __shfl_xor(sum_in,  sft);
        sq_in   += __shfl_xor(sq_in,   sft);
        sum_out += __shfl_xor(sum_out, sft);
        sq_out  += __shfl_xor(sq_out,  sft);
    }
    if (lane == 0) {
        partial[wib][0] = sum_in; partial[wib][1] = sq_in;
        partial[wib][2] = sum_out; partial[wib][3] = sq_out;
    }
    __syncthreads();
    if (lane == 0 && half == 0) {
        const float S_in = partial[wib][0] + partial[wib + 1][0];
        const float Q_in = partial[wib][1] + partial[wib + 1][1];
        const float S_out = partial[wib][2] + partial[wib + 1][2];
        const float Q_out = partial[wib][3] + partial[wib + 1][3];
        const float ni = 1024.f, no = 124.f;
        const float m_in = S_in / ni, m_out = S_out / no;
        const float v_in  = (Q_in  - ni * m_in  * m_in ) / (ni - 1.f);
        const float v_out = (Q_out - no * m_out * m_out) / (no - 1.f);
        const float contrast = (m_in - m_out) / sqrtf(v_in + v_out + 1e-8f);
        out[pid] = contrast * mask[pid];
    }
}

// ---------------- generic fallback ----------------
__global__ __launch_bounds__(256) void contrast_kernel_generic(
    const float* __restrict__ points, const float* __restrict__ mask,
    const float* __restrict__ img, const float* __restrict__ st_in,
    const float* __restrict__ st_out, float* __restrict__ out,
    int n_points, int n_in, int n_out, int Himg, int Wimg)
{
    const int wave = (int)((blockIdx.x * (unsigned)blockDim.x + threadIdx.x) >> 6);
    const int lane = (int)(threadIdx.x & 63u);
    if (wave >= n_points) return;
    const float* pt = points + (size_t)wave * 5;
    const float px = pt[0], py = pt[1], a = pt[2], b = pt[3], th = pt[4];
    float sn, cs; sincosf(th, &sn, &cs);
    const float A00 = a * cs, A01 = -b * sn, A10 = a * sn, A11 = b * cs;
    const float fImax = (float)(Himg - 2), fJmax = (float)(Wimg - 2);
    float sum_in = 0.f, sq_in = 0.f;
    for (int base = 0; base < n_in; base += 64) {
        const int n = base + lane;
        if (n < n_in) {
            const float sy = st_in[n * 3 + 0], sx = st_in[n * 3 + 1];
            const float ci = fmaf(A00, sy, fmaf(A01, sx, px));
            const float cj = fmaf(A10, sy, fmaf(A11, sx, py));
            const float fi = fminf(fmaxf(floorf(ci), 0.f), fImax);
            const float fj = fminf(fmaxf(floorf(cj), 0.f), fJmax);
            const float di = fminf(fmaxf(ci - fi, 0.f), 1.f);
            const float dj = fminf(fmaxf(cj - fj, 0.f), 1.f);
            const float* p0 = img + ((int)fi * Wimg + (int)fj);
            const float v00 = p0[0], v01 = p0[1], v10 = p0[Wimg], v11 = p0[Wimg + 1];
            const float top = fmaf(v01 - v00, dj, v00);
            const float bot = fmaf(v11 - v10, dj, v10);
            const float v = fmaf(bot - top, di, top);
            sum_in += v; sq_in = fmaf(v, v, sq_in);
        }
    }
    float sum_out = 0.f, sq_out = 0.f;
    for (int base = 0; base < n_out; base += 64) {
        const int n = base + lane;
        if (n < n_out) {
            const float sy = st_out[n * 3 + 0], sx = st_out[n * 3 + 1];
            const float ci = fmaf(A00, sy, fmaf(A01, sx, px));
            const float cj = fmaf(A10, sy, fmaf(A11, sx, py));
            const float fi = fminf(fmaxf(floorf(ci), 0.f), fImax);
            const float fj = fminf(fmaxf(floorf(cj), 0.f), fJmax);
            const float di = fminf(fmaxf(ci - fi, 0.f), 1.f);
            const float dj = fminf(fmaxf(cj - fj, 0.f), 1.f);
            const float* p0 = img + ((int)fi * Wimg + (int)fj);
            const float v00 = p0[0], v01 = p0[1], v10 = p0[Wimg], v11 = p0[Wimg + 1];
            const float top = fmaf(v01 - v00, dj, v00);
            const float bot = fmaf(v11 - v10, dj, v10);
            const float v = fmaf(bot - top, di, top);
            sum_out += v; sq_out = fmaf(v, v, sq_out);
        }
    }
    #pragma unroll
    for (int sft = 32; sft > 0; sft >>= 1) {
        sum_in += __shfl_xor(sum_in, sft);  sq_in += __shfl_xor(sq_in, sft);
        sum_out += __shfl_xor(sum_out, sft); sq_out += __shfl_xor(sq_out, sft);
    }
    if (lane == 0) {
        const float ni = (float)n_in, no = (float)n_out;
        const float m_in = sum_in / ni, m_out = sum_out / no;
        const float v_in = (sq_in - ni * m_in * m_in) / (ni - 1.f);
        const float v_out = (sq_out - no * m_out * m_out) / (no - 1.f);
        const float contrast = (m_in - m_out) / sqrtf(v_in + v_out + 1e-8f);
        out[wave] = contrast * mask[wave];
    }
}

extern "C" void kernel_launch(void* const* d_in, const int* in_sizes, int n_in_bufs,
                              void* d_out, int out_size, void* d_ws, size_t ws_size,
                              hipStream_t stream) {
    (void)n_in_bufs; (void)out_size;
    const float* points = (const float*)d_in[0];
    const float* mask   = (const float*)d_in[1];
    const float* img    = (const float*)d_in[2];
    const float* st_in  = (const float*)d_in[3];
    const float* st_out = (const float*)d_in[4];
    float* out = (float*)d_out;

    const int n_points = in_sizes[0] / 5;
    const int n_in     = in_sizes[3] / 3;
    const int n_out    = in_sizes[4] / 3;
    const int hw       = in_sizes[2];

    const bool canonical = (n_in == 1024 && n_out == 124 && hw == 2048 * 2048);

    // ws layout: [fp16 image | cnt[8] | cur[8] | off[8] | perm[n_points]]
    const size_t img_bytes = (size_t)hw * sizeof(__half);
    const size_t meta_off  = (img_bytes + 255) & ~(size_t)255;
    const size_t need      = meta_off + (size_t)(24 + n_points) * 4 + 64;

    if (canonical && ws_size >= need && n_points > 0) {
        __half* img16 = (__half*)d_ws;
        int* meta = (int*)((char*)d_ws + meta_off);
        int* cnt  = meta;        // [0..7]
        int* cur  = meta + 8;    // [8..15]
        int* off  = meta + 16;   // [16..23]
        int* perm = meta + 24;

        const int nb = (n_points + 255) / 256;
        bin_init       <<<1,  64, 0, stream>>>(meta);
        bin_count_lds  <<<nb, 256, 0, stream>>>(points, n_points, cnt);
        bin_offsets    <<<1,  64, 0, stream>>>(cnt, off);
        bin_scatter_lds<<<nb, 256, 0, stream>>>(points, n_points, off, cur, perm);
        convert_img_f16<<<2048, 256, 0, stream>>>((const float4*)img, (uint4*)img16);
        contrast_kernel_f16_binned<<<8 * MAIN_PAIR_STRIDE, 256, 0, stream>>>(
            points, mask, img16, perm, cnt, off, out);
    } else if (canonical) {
        const int blocks = (n_points + 1) / 2;
        contrast_kernel_fast<<<blocks, 256, 0, stream>>>(points, mask, img, out, n_points);
    } else {
        int Wimg = 1;
        while ((long long)Wimg * Wimg < (long long)hw) Wimg <<= 1;
        const int Himg = hw / Wimg;
        const int blocks = (n_points + 3) / 4;
        contrast_kernel_generic<<<blocks, 256, 0, stream>>>(points, mask, img, st_in, st_out,
                                                            out, n_points, n_in, n_out, Himg, Wimg);
    }
}

// Round 7
// 117.683 us; speedup vs baseline: 2.4145x; 1.1501x over previous
//
#include <hip/hip_runtime.h>
#include <hip/hip_fp16.h>
#include <math.h>

// R7: two fixes aimed at the observed ~2000 cyc/point invariant:
// (1) image copied to fp16 with row stride 2080 (4160 B = 65 cache lines,
//     odd -> consecutive image rows hit distinct L1 sets; the original
//     4096/8192 B stride collapses a point's footprint onto ~3 sets).
// (2) occupancy-first gather: 1 wave/point, no LDS, rolled loop,
//     __launch_bounds__(256,8) caps VGPR at 64 -> 8 waves/SIMD.
//     (R1 at 70% occupancy processed scattered loads 2.4x faster per
//     instruction than every ~30%-occupancy variant since.)

#define PSTRIDE 2080   // padded row stride in halves (4160 B, 65 lines)

__global__ __launch_bounds__(256) void convert_img_f16_pad(
    const float4* __restrict__ src, __half* __restrict__ dst)
{
    const int row = (int)blockIdx.x;          // 2048 rows
    const int t   = (int)threadIdx.x;         // 256 lanes x 8 texels
    const float4 a = src[(size_t)row * 512 + t * 2];
    const float4 b = src[(size_t)row * 512 + t * 2 + 1];
    union { __half2 h[4]; uint4 u; } o;
    o.h[0] = __float22half2_rn(make_float2(a.x, a.y));
    o.h[1] = __float22half2_rn(make_float2(a.z, a.w));
    o.h[2] = __float22half2_rn(make_float2(b.x, b.y));
    o.h[3] = __float22half2_rn(make_float2(b.z, b.w));
    *(uint4*)(dst + (size_t)row * PSTRIDE + t * 8) = o.u;
}

template<bool CLAMP>
__device__ __forceinline__ float tap_pad(const __half* __restrict__ img,
                                         float ci, float cj)
{
    float fi = floorf(ci), fj = floorf(cj);
    if (CLAMP) {
        fi = fminf(fmaxf(fi, 0.f), 2046.f);
        fj = fminf(fmaxf(fj, 0.f), 2046.f);
    }
    float di = ci - fi, dj = cj - fj;
    if (CLAMP) {
        di = fminf(fmaxf(di, 0.f), 1.f);
        dj = fminf(fmaxf(dj, 0.f), 1.f);
    }
    const int r = (int)fi, c = (int)fj;
    const int base = (r << 11) + (r << 5) + c;   // r*2080 + c
    const int even = base & ~1;
    const int sh   = (base & 1) << 4;
    uint2 q0, q1;
    __builtin_memcpy(&q0, img + even, 8);               // 4 B aligned
    __builtin_memcpy(&q1, img + even + PSTRIDE, 8);
    const unsigned p0 = (unsigned)((((unsigned long long)q0.y << 32) | q0.x) >> sh);
    const unsigned p1 = (unsigned)((((unsigned long long)q1.y << 32) | q1.x) >> sh);
    const float2 f0 = __half22float2(*reinterpret_cast<const __half2*>(&p0));
    const float2 f1 = __half22float2(*reinterpret_cast<const __half2*>(&p1));
    const float top = fmaf(f0.y - f0.x, dj, f0.x);
    const float bot = fmaf(f1.y - f1.x, dj, f1.x);
    return fmaf(bot - top, di, top);
}

template<bool CLAMP>
__device__ __forceinline__ void accum_pad(
    const __half* __restrict__ img, int lane,
    float A00, float A01, float A10, float A11, float px, float py,
    float& sum_in, float& sq_in, float& sum_out, float& sq_out)
{
    // interior: 1024 samples, 16 iterations of 2 rows x 32 cols
    const float sx = fmaf((float)(lane & 31), 0.0625f, 0.03125f) - 1.0f;
    const int   hi = lane >> 5;
    const float bi = fmaf(A01, sx, px);
    const float bj = fmaf(A11, sx, py);

    float s0 = 0.f, q0 = 0.f, s1 = 0.f, q1 = 0.f;
    #pragma unroll 2
    for (int it = 0; it < 16; ++it) {
        const float sy = fmaf((float)(2 * it + hi), 0.0625f, 0.03125f) - 1.0f;
        const float ci = fmaf(A00, sy, bi);
        const float cj = fmaf(A10, sy, bj);
        const float v  = tap_pad<CLAMP>(img, ci, cj);
        if (it & 1) { s1 += v; q1 = fmaf(v, v, q1); }
        else        { s0 += v; q0 = fmaf(v, v, q0); }
    }
    sum_in = s0 + s1;
    sq_in  = q0 + q1;

    // ring: 124 samples, 2 iterations
    sum_out = 0.f; sq_out = 0.f;
    #pragma unroll
    for (int base = 0; base < 124; base += 64) {
        const int n = base + lane;
        if (n < 124) {
            int row, col;
            if (n < 32)      { row = 0;                   col = n; }
            else if (n < 92) { row = 1 + ((n - 32) >> 1); col = (n & 1) * 31; }
            else             { row = 31;                  col = n - 92; }
            const float sy = (fmaf((float)row, 0.0625f, 0.03125f) - 1.0f) * 1.0625f;
            const float sxo = (fmaf((float)col, 0.0625f, 0.03125f) - 1.0f) * 1.0625f;
            const float ci = fmaf(A00, sy, fmaf(A01, sxo, px));
            const float cj = fmaf(A10, sy, fmaf(A11, sxo, py));
            const float v  = tap_pad<CLAMP>(img, ci, cj);
            sum_out += v;
            sq_out = fmaf(v, v, sq_out);
        }
    }
}

__global__ __launch_bounds__(256, 8) void contrast_f16_pad(
    const float* __restrict__ points,
    const float* __restrict__ mask,
    const __half* __restrict__ img,     // padded fp16 in ws
    float* __restrict__ out,
    int n_points)
{
    const int wave = (int)((blockIdx.x * (unsigned)blockDim.x + threadIdx.x) >> 6);
    const int lane = (int)(threadIdx.x & 63u);
    if (wave >= n_points) return;

    const float* pt = points + (size_t)wave * 5;
    const float px = pt[0];
    const float py = pt[1];
    const float a  = pt[2];
    const float b  = pt[3];
    const float th = pt[4];

    float sn, cs;
    sincosf(th, &sn, &cs);
    const float A00 = a * cs, A01 = -b * sn;   // i (row)
    const float A10 = a * sn, A11 =  b * cs;   // j (col)

    const float Ri = (fabsf(A00) + fabsf(A01)) * 1.04f;
    const float Rj = (fabsf(A10) + fabsf(A11)) * 1.04f;
    const bool interior = (px >= Ri + 0.5f) && (px <= 2046.0f - Ri) &&
                          (py >= Rj + 0.5f) && (py <= 2046.0f - Rj);

    float sum_in, sq_in, sum_out, sq_out;
    if (interior) {
        accum_pad<false>(img, lane, A00, A01, A10, A11, px, py,
                         sum_in, sq_in, sum_out, sq_out);
    } else {
        accum_pad<true>(img, lane, A00, A01, A10, A11, px, py,
                        sum_in, sq_in, sum_out, sq_out);
    }

    #pragma unroll
    for (int off = 32; off > 0; off >>= 1) {
        sum_in  += __shfl_xor(sum_in,  off);
        sq_in   += __shfl_xor(sq_in,   off);
        sum_out += __shfl_xor(sum_out, off);
        sq_out  += __shfl_xor(sq_out,  off);
    }

    if (lane == 0) {
        const float ni = 1024.f, no = 124.f;
        const float m_in  = sum_in  / ni;
        const float m_out = sum_out / no;
        const float v_in  = (sq_in  - ni * m_in  * m_in ) / (ni - 1.f);
        const float v_out = (sq_out - no * m_out * m_out) / (no - 1.f);
        const float contrast = (m_in - m_out) / sqrtf(v_in + v_out + 1e-8f);
        out[wave] = contrast * mask[wave];
    }
}

// ---------------- fp32 fast path (no-ws fallback) ----------------
__global__ __launch_bounds__(256) void contrast_kernel_fast(
    const float* __restrict__ points, const float* __restrict__ mask,
    const float* __restrict__ img, float* __restrict__ out, int n_points)
{
    constexpr int W = 2048;
    constexpr float fImax = 2046.f, fJmax = 2046.f;
    const int wave = (int)((blockIdx.x * (unsigned)blockDim.x + threadIdx.x) >> 6);
    const int lane = (int)(threadIdx.x & 63u);
    if (wave >= n_points) return;
    const float* pt = points + (size_t)wave * 5;
    const float px = pt[0], py = pt[1], a = pt[2], b = pt[3], th = pt[4];
    float sn, cs; sincosf(th, &sn, &cs);
    const float A00 = a * cs, A01 = -b * sn, A10 = a * sn, A11 = b * cs;
    const float sx = fmaf((float)(lane & 31), 0.0625f, 0.03125f) - 1.0f;
    const int hi = lane >> 5;
    const float bi = fmaf(A01, sx, px);
    const float bj = fmaf(A11, sx, py);
    float s0 = 0.f, q0 = 0.f, s1 = 0.f, q1 = 0.f;
    #pragma unroll 2
    for (int it = 0; it < 16; ++it) {
        const float sy = fmaf((float)(2 * it + hi), 0.0625f, 0.03125f) - 1.0f;
        const float ci = fmaf(A00, sy, bi);
        const float cj = fmaf(A10, sy, bj);
        const float fi = fminf(fmaxf(floorf(ci), 0.f), fImax);
        const float fj = fminf(fmaxf(floorf(cj), 0.f), fJmax);
        const float di = fminf(fmaxf(ci - fi, 0.f), 1.f);
        const float dj = fminf(fmaxf(cj - fj, 0.f), 1.f);
        const float* p0 = img + (((int)fi << 11) + (int)fj);
        float2 r0, r1;
        __builtin_memcpy(&r0, p0, sizeof(float2));
        __builtin_memcpy(&r1, p0 + W, sizeof(float2));
        const float top = fmaf(r0.y - r0.x, dj, r0.x);
        const float bot = fmaf(r1.y - r1.x, dj, r1.x);
        const float v = fmaf(bot - top, di, top);
        if (it & 1) { s1 += v; q1 = fmaf(v, v, q1); }
        else        { s0 += v; q0 = fmaf(v, v, q0); }
    }
    float sum_in = s0 + s1, sq_in = q0 + q1;
    float sum_out = 0.f, sq_out = 0.f;
    #pragma unroll
    for (int base = 0; base < 124; base += 64) {
        const int n = base + lane;
        if (n < 124) {
            int row, col;
            if (n < 32)      { row = 0;                   col = n; }
            else if (n < 92) { row = 1 + ((n - 32) >> 1); col = (n & 1) * 31; }
            else             { row = 31;                  col = n - 92; }
            const float sy = (fmaf((float)row, 0.0625f, 0.03125f) - 1.0f) * 1.0625f;
            const float sxo = (fmaf((float)col, 0.0625f, 0.03125f) - 1.0f) * 1.0625f;
            const float ci = fmaf(A00, sy, fmaf(A01, sxo, px));
            const float cj = fmaf(A10, sy, fmaf(A11, sxo, py));
            const float fi = fminf(fmaxf(floorf(ci), 0.f), fImax);
            const float fj = fminf(fmaxf(floorf(cj), 0.f), fJmax);
            const float di = fminf(fmaxf(ci - fi, 0.f), 1.f);
            const float dj = fminf(fmaxf(cj - fj, 0.f), 1.f);
            const float* p0 = img + (((int)fi << 11) + (int)fj);
            float2 r0, r1;
            __builtin_memcpy(&r0, p0, sizeof(float2));
            __builtin_memcpy(&r1, p0 + W, sizeof(float2));
            const float top = fmaf(r0.y - r0.x, dj, r0.x);
            const float bot = fmaf(r1.y - r1.x, dj, r1.x);
            const float v = fmaf(bot - top, di, top);
            sum_out += v; sq_out = fmaf(v, v, sq_out);
        }
    }
    #pragma unroll
    for (int off = 32; off > 0; off >>= 1) {
        sum_in  += __shfl_xor(sum_in,  off);
        sq_in   += __shfl_xor(sq_in,   off);
        sum_out += __shfl_xor(sum_out, off);
        sq_out  += __shfl_xor(sq_out,  off);
    }
    if (lane == 0) {
        const float ni = 1024.f, no = 124.f;
        const float m_in = sum_in / ni, m_out = sum_out / no;
        const float v_in  = (sq_in  - ni * m_in  * m_in ) / (ni - 1.f);
        const float v_out = (sq_out - no * m_out * m_out) / (no - 1.f);
        const float contrast = (m_in - m_out) / sqrtf(v_in + v_out + 1e-8f);
        out[wave] = contrast * mask[wave];
    }
}

// ---------------- generic fallback ----------------
__global__ __launch_bounds__(256) void contrast_kernel_generic(
    const float* __restrict__ points, const float* __restrict__ mask,
    const float* __restrict__ img, const float* __restrict__ st_in,
    const float* __restrict__ st_out, float* __restrict__ out,
    int n_points, int n_in, int n_out, int Himg, int Wimg)
{
    const int wave = (int)((blockIdx.x * (unsigned)blockDim.x + threadIdx.x) >> 6);
    const int lane = (int)(threadIdx.x & 63u);
    if (wave >= n_points) return;
    const float* pt = points + (size_t)wave * 5;
    const float px = pt[0], py = pt[1], a = pt[2], b = pt[3], th = pt[4];
    float sn, cs; sincosf(th, &sn, &cs);
    const float A00 = a * cs, A01 = -b * sn, A10 = a * sn, A11 = b * cs;
    const float fImax = (float)(Himg - 2), fJmax = (float)(Wimg - 2);
    float sum_in = 0.f, sq_in = 0.f;
    for (int base = 0; base < n_in; base += 64) {
        const int n = base + lane;
        if (n < n_in) {
            const float sy = st_in[n * 3 + 0], sx = st_in[n * 3 + 1];
            const float ci = fmaf(A00, sy, fmaf(A01, sx, px));
            const float cj = fmaf(A10, sy, fmaf(A11, sx, py));
            const float fi = fminf(fmaxf(floorf(ci), 0.f), fImax);
            const float fj = fminf(fmaxf(floorf(cj), 0.f), fJmax);
            const float di = fminf(fmaxf(ci - fi, 0.f), 1.f);
            const float dj = fminf(fmaxf(cj - fj, 0.f), 1.f);
            const float* p0 = img + ((int)fi * Wimg + (int)fj);
            const float v00 = p0[0], v01 = p0[1], v10 = p0[Wimg], v11 = p0[Wimg + 1];
            const float top = fmaf(v01 - v00, dj, v00);
            const float bot = fmaf(v11 - v10, dj, v10);
            const float v = fmaf(bot - top, di, top);
            sum_in += v; sq_in = fmaf(v, v, sq_in);
        }
    }
    float sum_out = 0.f, sq_out = 0.f;
    for (int base = 0; base < n_out; base += 64) {
        const int n = base + lane;
        if (n < n_out) {
            const float sy = st_out[n * 3 + 0], sx = st_out[n * 3 + 1];
            const float ci = fmaf(A00, sy, fmaf(A01, sx, px));
            const float cj = fmaf(A10, sy, fmaf(A11, sx, py));
            const float fi = fminf(fmaxf(floorf(ci), 0.f), fImax);
            const float fj = fminf(fmaxf(floorf(cj), 0.f), fJmax);
            const float di = fminf(fmaxf(ci - fi, 0.f), 1.f);
            const float dj = fminf(fmaxf(cj - fj, 0.f), 1.f);
            const float* p0 = img + ((int)fi * Wimg + (int)fj);
            const float v00 = p0[0], v01 = p0[1], v10 = p0[Wimg], v11 = p0[Wimg + 1];
            const float top = fmaf(v01 - v00, dj, v00);
            const float bot = fmaf(v11 - v10, dj, v10);
            const float v = fmaf(bot - top, di, top);
            sum_out += v; sq_out = fmaf(v, v, sq_out);
        }
    }
    #pragma unroll
    for (int off = 32; off > 0; off >>= 1) {
        sum_in += __shfl_xor(sum_in, off);  sq_in += __shfl_xor(sq_in, off);
        sum_out += __shfl_xor(sum_out, off); sq_out += __shfl_xor(sq_out, off);
    }
    if (lane == 0) {
        const float ni = (float)n_in, no = (float)n_out;
        const float m_in = sum_in / ni, m_out = sum_out / no;
        const float v_in = (sq_in - ni * m_in * m_in) / (ni - 1.f);
        const float v_out = (sq_out - no * m_out * m_out) / (no - 1.f);
        const float contrast = (m_in - m_out) / sqrtf(v_in + v_out + 1e-8f);
        out[wave] = contrast * mask[wave];
    }
}

extern "C" void kernel_launch(void* const* d_in, const int* in_sizes, int n_in_bufs,
                              void* d_out, int out_size, void* d_ws, size_t ws_size,
                              hipStream_t stream) {
    (void)n_in_bufs; (void)out_size;
    const float* points = (const float*)d_in[0];
    const float* mask   = (const float*)d_in[1];
    const float* img    = (const float*)d_in[2];
    const float* st_in  = (const float*)d_in[3];
    const float* st_out = (const float*)d_in[4];
    float* out = (float*)d_out;

    const int n_points = in_sizes[0] / 5;
    const int n_in     = in_sizes[3] / 3;
    const int n_out    = in_sizes[4] / 3;
    const int hw       = in_sizes[2];

    const bool canonical = (n_in == 1024 && n_out == 124 && hw == 2048 * 2048);
    const size_t pad_bytes = (size_t)2048 * PSTRIDE * sizeof(__half) + 64;

    if (canonical && ws_size >= pad_bytes) {
        __half* img16 = (__half*)d_ws;
        convert_img_f16_pad<<<2048, 256, 0, stream>>>((const float4*)img, img16);
        contrast_f16_pad<<<(n_points + 3) / 4, 256, 0, stream>>>(
            points, mask, img16, out, n_points);
    } else if (canonical) {
        contrast_kernel_fast<<<(n_points + 3) / 4, 256, 0, stream>>>(
            points, mask, img, out, n_points);
    } else {
        int Wimg = 1;
        while ((long long)Wimg * Wimg < (long long)hw) Wimg <<= 1;
        const int Himg = hw / Wimg;
        contrast_kernel_generic<<<(n_points + 3) / 4, 256, 0, stream>>>(
            points, mask, img, st_in, st_out, out, n_points, n_in, n_out, Himg, Wimg);
    }
}